// Round 6
// baseline (491.245 us; speedup 1.0000x reference)
//
#include <hip/hip_runtime.h>
#include <cstdint>
#include <cstddef>

// ---------------------------------------------------------------------------
// R11: - k_step retiled 32x64 -> 32x32 (P:1024 + C:512 = 1536 blocks = 6/CU,
//        was 768 = 3/CU grid-capped). Latency-bound kernel -> TLP is the
//        hiding resource. 3-slot A/B VGPR rings, acc[2][2], red LDS 16KB,
//        ~84 VGPR @ __launch_bounds__(256,6). Weight traffic unchanged and
//        still XCD-local (bid%8 == nt%8); A traffic doubles (latency-bound,
//        acceptable). Epilogue: wave w -> (i=w>>1, j=w&1).
//      - 5 weight-prep kernels fused into one k_wprep (range dispatch),
//        removes 4 dispatch boundaries.
//      - k_gemm_big / k_prep unchanged (R10 form, 385us, absmax 0.0039).
// ---------------------------------------------------------------------------

typedef _Float16 half8 __attribute__((ext_vector_type(8)));
typedef float floatx4 __attribute__((ext_vector_type(4)));

__device__ __forceinline__ void async_cp16(const void* g, void* l) {
  __builtin_amdgcn_global_load_lds(
      (const __attribute__((address_space(1))) void*)g,
      (__attribute__((address_space(3))) void*)l, 16, 0, 0);
}

__device__ __forceinline__ float sigmoidf_(float x) {
  return 1.f / (1.f + __expf(-x));
}

// ---- transpose fp32 [K][N] tile -> f16 dst[n][k]
__device__ __forceinline__ void transpose_dev(
    const float* __restrict__ src, int N, _Float16* __restrict__ dst,
    int dst_ld, int k_off, int bx, int by, float (*tile)[65]) {
  const int k0 = by * 64, n0 = bx * 64;
  const int tx = threadIdx.x & 63, ty = threadIdx.x >> 6;
#pragma unroll
  for (int j = 0; j < 16; ++j) {
    int kr = j * 4 + ty;
    tile[kr][tx] = src[(size_t)(k0 + kr) * N + n0 + tx];
  }
  __syncthreads();
#pragma unroll
  for (int j = 0; j < 16; ++j) {
    int nr = j * 4 + ty;
    dst[(size_t)(n0 + nr) * dst_ld + k_off + k0 + tx] = (_Float16)tile[tx][nr];
  }
}

// ---- pack fp32 src [K][N] tile into MFMA B-fragment order f16
__device__ __forceinline__ void pack_dev(
    const float* __restrict__ src, int N, _Float16* __restrict__ dst,
    int kStride, int kOffChunks, int bx, int by, float (*tile)[65]) {
  const int k0 = by * 64, n0 = bx * 64;
  const int tx = threadIdx.x & 63, ty = threadIdx.x >> 6;
#pragma unroll
  for (int jj = 0; jj < 16; ++jj) {
    int kr = jj * 4 + ty;
    tile[kr][tx] = src[(size_t)(k0 + kr) * N + n0 + tx];
  }
  __syncthreads();
  const int j = threadIdx.x >> 6, lane = threadIdx.x & 63;
  const int r16 = lane & 15, quad = lane >> 4;
#pragma unroll
  for (int c = 0; c < 2; ++c) {
    half8 v;
#pragma unroll
    for (int u = 0; u < 8; ++u)
      v[u] = (_Float16)tile[c * 32 + quad * 8 + u][j * 16 + r16];
    const int kcG = kOffChunks + by * 2 + c;
    *(half8*)(dst + ((size_t)(bx * kStride + kcG) * 4 + j) * 512 + lane * 8) = v;
  }
}

// ---- all weight prep in one dispatch (ranges of the 1024-block grid)
__global__ __launch_bounds__(256) void k_wprep(
    const float* __restrict__ w_oh, const float* __restrict__ w_hp,
    const float* __restrict__ w_pp, const float* __restrict__ w_cp,
    const float* __restrict__ w_pc, _Float16* __restrict__ WohT,
    _Float16* __restrict__ Whp, _Float16* __restrict__ Wrf,
    _Float16* __restrict__ Wcf) {
  __shared__ float tile[64][65];
  const int blk = blockIdx.x;
  if (blk < 256) {
    transpose_dev(w_oh, 1024, WohT, 1024, 0, blk & 15, blk >> 4, tile);
  } else if (blk < 512) {
    const int t = blk - 256;
    transpose_dev(w_hp, 1024, Whp, 1024, 0, t & 15, t >> 4, tile);
  } else if (blk < 768) {
    const int t = blk - 512;
    pack_dev(w_pp, 1024, Wrf, 48, 0, t & 15, t >> 4, tile);
  } else if (blk < 896) {
    const int t = blk - 768;
    pack_dev(w_cp, 1024, Wrf, 48, 32, t & 15, t >> 4, tile);
  } else {
    const int t = blk - 896;
    pack_dev(w_pc, 512, Wcf, 32, 0, t & 7, t >> 3, tile);
  }
}

// ---- prefix scan over t of x (decay 0.75) -> U f16 [11][1024][1024]; inits
__global__ __launch_bounds__(256) void k_prep(
    const float* __restrict__ x, _Float16* __restrict__ U,
    _Float16* __restrict__ AH0, _Float16* __restrict__ AP0,
    _Float16* __restrict__ AC0, float* __restrict__ Pst,
    float* __restrict__ Cst) {
  const int id = blockIdx.x * 256 + threadIdx.x;  // 0 .. 1M-1
  const int b = id >> 10, i = id & 1023;
  const float* xb = x + (size_t)b * 12 * 1024 + i;
  float g = 0.f;
#pragma unroll
  for (int t = 0; t < 11; ++t) {
    g = xb[t * 1024] + 0.75f * g;
    U[(size_t)t * 1048576 + id] = (_Float16)g;
  }
  AH0[id] = (_Float16)0.5f;
  AP0[id] = (_Float16)0.5f;
  Pst[id] = 0.f;
  if (i < 512) {
    AC0[b * 512 + i] = (_Float16)0.5f;
    Cst[b * 512 + i] = 0.f;
  }
}

// ---- big GEMM, K=1024, 128x128 tile, 4 waves, BK=64 single-buffer LDS,
//      global_load_lds staging, 2-barrier K-loop, XCD y-chunk swizzle. (R10)
__global__ __launch_bounds__(256, 3) void k_gemm_big(
    const _Float16* __restrict__ A, const _Float16* __restrict__ B,
    const float* __restrict__ bias, _Float16* __restrict__ dst, int mode) {
  __shared__ __align__(16) _Float16 sA[128 * 64];
  __shared__ __align__(16) _Float16 sB[128 * 64];
  const int tid = threadIdx.x;
  const int lane = tid & 63, w = tid >> 6;
  const int lin = blockIdx.x;
  const int chunk = gridDim.x >> 6;  // = NY/8 (11 or 12)
  const int xcd = lin & 7;
  const int j0 = lin >> 3;
  const int bx = j0 & 7;
  const int by = xcd * chunk + (j0 >> 3);
  const int mBase = by * 128, nBase = bx * 128;
  const int r16 = lane & 15, quad = lane >> 4;
  const int lrow = lane >> 3;
  const int gsw = ((lane & 7) ^ lrow) * 8;
  const int wr = w >> 1, wc = w & 1;

  const floatx4 zero = {0.f, 0.f, 0.f, 0.f};
  floatx4 acc[4][4];
#pragma unroll
  for (int i = 0; i < 4; ++i)
#pragma unroll
    for (int j = 0; j < 4; ++j) acc[i][j] = zero;

  const _Float16* Abase = A + (size_t)(mBase + w * 32 + lrow) * 1024 + gsw;
  const _Float16* Bbase = B + (size_t)(nBase + w * 32 + lrow) * 1024 + gsw;
  _Float16* sAw = sA + (w * 32) * 64;
  _Float16* sBw = sB + (w * 32) * 64;
  const _Float16* sa = sA + (size_t)wr * 64 * 64;
  const _Float16* sb = sB + (size_t)wc * 64 * 64;

  for (int kt = 0; kt < 16; ++kt) {
    const int k0 = kt << 6;
#pragma unroll
    for (int q = 0; q < 4; ++q)
      async_cp16(Abase + (size_t)q * 8192 + k0, sAw + q * 512);
#pragma unroll
    for (int q = 0; q < 4; ++q)
      async_cp16(Bbase + (size_t)q * 8192 + k0, sBw + q * 512);
    asm volatile("s_waitcnt vmcnt(0)" ::: "memory");
    __syncthreads();
#pragma unroll
    for (int kk = 0; kk < 2; ++kk) {
      const int sw = ((kk * 4 + quad) ^ (r16 & 7)) * 8;
      half8 af[4], bf[4];
#pragma unroll
      for (int i = 0; i < 4; ++i)
        af[i] = *(const half8*)&sa[(i * 16 + r16) * 64 + sw];
#pragma unroll
      for (int j = 0; j < 4; ++j)
        bf[j] = *(const half8*)&sb[(j * 16 + r16) * 64 + sw];
#pragma unroll
      for (int i = 0; i < 4; ++i)
#pragma unroll
        for (int j = 0; j < 4; ++j)
          acc[i][j] = __builtin_amdgcn_mfma_f32_16x16x32_f16(af[i], bf[j],
                                                             acc[i][j], 0, 0, 0);
    }
    __syncthreads();
  }

  if (mode == 0) {
    const int tm1 = mBase >> 10;
    const float beta = 1.f - __powf(0.75f, (float)(tm1 + 1));
    _Float16* o = dst + (size_t)(mBase + 1024) * 1024;
#pragma unroll
    for (int i = 0; i < 4; ++i)
#pragma unroll
      for (int j = 0; j < 4; ++j) {
        const int n = nBase + wc * 64 + j * 16 + r16;
#pragma unroll
        for (int r = 0; r < 4; ++r) {
          const int row = wr * 64 + i * 16 + quad * 4 + r;
          const float h = 0.25f * acc[i][j][r] + beta * bias[n];
          o[(size_t)row * 1024 + n] = (_Float16)sigmoidf_(h);
        }
      }
  } else {
    _Float16* o = dst + (size_t)mBase * 1024;
#pragma unroll
    for (int i = 0; i < 4; ++i)
#pragma unroll
      for (int j = 0; j < 4; ++j) {
        const int n = nBase + wc * 64 + j * 16 + r16;
#pragma unroll
        for (int r = 0; r < 4; ++r) {
          const int row = wr * 64 + i * 16 + quad * 4 + r;
          o[(size_t)row * 1024 + n] = (_Float16)(0.25f * (acc[i][j][r] + bias[n]));
        }
      }
  }
}

// ---- one recurrent step: 32m x 32n tiles, 4-wave split-K, LDS reduce.
// blocks 0..1023:   P tiles, K=1536 (12 chunks/wave) over [a_p|a_c]
// blocks 1024..1535: C tiles, K=1024 (8 chunks/wave) over a_p
// 1536 blocks = 6/CU. A/B via 3-slot VGPR rings (2 ahead). Epilogue
// operands prefetched before the raw-barrier reduction (no vm drain).
__global__ __launch_bounds__(256, 6) void k_step(
    const _Float16* __restrict__ Qt, const _Float16* __restrict__ APc,
    const _Float16* __restrict__ ACc, _Float16* __restrict__ APn,
    _Float16* __restrict__ ACn, const _Float16* __restrict__ Wrf,
    const _Float16* __restrict__ Wcf, const float* __restrict__ bias_c,
    float* __restrict__ Pst, float* __restrict__ Cst,
    float* __restrict__ out_t) {
  __shared__ float red[4][2][2][4][64];  // 16 KB
  const int lane = threadIdx.x & 63, w = threadIdx.x >> 6;
  const int r16 = lane & 15, quad = lane >> 4;
  const int blk = blockIdx.x;
  const bool isP = blk < 1024;
  int mBase, nBase, ntG, jhalf;
  if (isP) {
    mBase = (blk >> 5) * 32;
    const int nt = blk & 31;
    nBase = nt * 32; ntG = nt >> 1; jhalf = nt & 1;
  } else {
    const int b = blk - 1024;
    mBase = (b >> 4) * 32;
    const int nt = b & 15;
    nBase = nt * 32; ntG = nt >> 1; jhalf = nt & 1;
  }
  const floatx4 zero = {0.f, 0.f, 0.f, 0.f};
  floatx4 acc[2][2];
#pragma unroll
  for (int i = 0; i < 2; ++i)
#pragma unroll
    for (int j = 0; j < 2; ++j) acc[i][j] = zero;

  half8 abuf[3][2], bbuf[3][2];
  auto MM = [&](half8* af, half8* bf) {
#pragma unroll
    for (int i = 0; i < 2; ++i)
#pragma unroll
      for (int j = 0; j < 2; ++j)
        acc[i][j] = __builtin_amdgcn_mfma_f32_16x16x32_f16(af[i], bf[j],
                                                           acc[i][j], 0, 0, 0);
  };

  if (isP) {
    const int kcBase = w * 12;
    auto LDA = [&](int c) {
      const int kc = kcBase + c, kg = kc * 32;
      half8* af = abuf[c % 3];
      if (kc < 32) {
        af[0] = *(const half8*)(APc + (size_t)(mBase + r16) * 1024 + kg + quad * 8);
        af[1] = *(const half8*)(APc + (size_t)(mBase + 16 + r16) * 1024 + kg + quad * 8);
      } else {
        af[0] = *(const half8*)(ACc + (size_t)(mBase + r16) * 512 + (kg - 1024) + quad * 8);
        af[1] = *(const half8*)(ACc + (size_t)(mBase + 16 + r16) * 512 + (kg - 1024) + quad * 8);
      }
    };
    auto LDB = [&](int c) {
      const int kc = kcBase + c;
      const _Float16* wp =
          Wrf + ((size_t)(ntG * 48 + kc) * 4 + jhalf * 2) * 512 + lane * 8;
      half8* bf = bbuf[c % 3];
      bf[0] = *(const half8*)(wp);
      bf[1] = *(const half8*)(wp + 512);
    };
    LDA(0); LDA(1); LDA(2);
    LDB(0); LDB(1); LDB(2);
#pragma unroll
    for (int c = 0; c < 12; ++c) {
      MM(abuf[c % 3], bbuf[c % 3]);
      if (c + 3 < 12) { LDB(c + 3); LDA(c + 3); }
    }
  } else {
    const int kcBase = w * 8;
    auto LDA = [&](int c) {
      const int kc = kcBase + c, kg = kc * 32;
      half8* af = abuf[c % 3];
      af[0] = *(const half8*)(APc + (size_t)(mBase + r16) * 1024 + kg + quad * 8);
      af[1] = *(const half8*)(APc + (size_t)(mBase + 16 + r16) * 1024 + kg + quad * 8);
    };
    auto LDB = [&](int c) {
      const int kc = kcBase + c;
      const _Float16* wp =
          Wcf + ((size_t)(ntG * 32 + kc) * 4 + jhalf * 2) * 512 + lane * 8;
      half8* bf = bbuf[c % 3];
      bf[0] = *(const half8*)(wp);
      bf[1] = *(const half8*)(wp + 512);
    };
    LDA(0); LDA(1); LDA(2);
    LDB(0); LDB(1); LDB(2);
#pragma unroll
    for (int c = 0; c < 8; ++c) {
      MM(abuf[c % 3], bbuf[c % 3]);
      if (c + 3 < 8) { LDB(c + 3); LDA(c + 3); }
    }
  }

  // ---- epilogue operand prefetch (rides across the reduction barrier)
  const int i_ep = w >> 1, j_ep = w & 1;
  const int n_ep = nBase + j_ep * 16 + r16;
  _Float16 qv[4];
  float sv[4];
  float biasn = 0.f;
  if (isP) {
#pragma unroll
    for (int r = 0; r < 4; ++r) {
      const size_t o = (size_t)(mBase + i_ep * 16 + quad * 4 + r) * 1024 + n_ep;
      qv[r] = Qt[o];
      sv[r] = Pst[o];
    }
  } else {
    biasn = bias_c[n_ep];
#pragma unroll
    for (int r = 0; r < 4; ++r) {
      const size_t o = (size_t)(mBase + i_ep * 16 + quad * 4 + r) * 512 + n_ep;
      sv[r] = Cst[o];
    }
  }

  // cross-wave K reduction (raw barrier: wait own ds_writes only, no vm drain)
#pragma unroll
  for (int i = 0; i < 2; ++i)
#pragma unroll
    for (int j = 0; j < 2; ++j)
#pragma unroll
      for (int r = 0; r < 4; ++r) red[w][i][j][r][lane] = acc[i][j][r];
  asm volatile("s_waitcnt lgkmcnt(0)" ::: "memory");
  __builtin_amdgcn_s_barrier();

  if (isP) {
#pragma unroll
    for (int r = 0; r < 4; ++r) {
      float v = 0.f;
#pragma unroll
      for (int q = 0; q < 4; ++q) v += red[q][i_ep][j_ep][r][lane];
      const int b = mBase + i_ep * 16 + quad * 4 + r;
      const size_t o = (size_t)b * 1024 + n_ep;
      const float pn = 0.25f * v + (float)qv[r] + 0.75f * sv[r];
      Pst[o] = pn;
      const float a = sigmoidf_(pn);
      APn[o] = (_Float16)a;
      if (out_t) out_t[o] = a;
    }
  } else {
#pragma unroll
    for (int r = 0; r < 4; ++r) {
      float v = 0.f;
#pragma unroll
      for (int q = 0; q < 4; ++q) v += red[q][i_ep][j_ep][r][lane];
      const int b = mBase + i_ep * 16 + quad * 4 + r;
      const size_t o = (size_t)b * 512 + n_ep;
      const float cn = 0.25f * (v + biasn) + 0.75f * sv[r];
      Cst[o] = cn;
      ACn[o] = (_Float16)sigmoidf_(cn);
    }
  }
}

extern "C" void kernel_launch(void* const* d_in, const int* in_sizes, int n_in,
                              void* d_out, int out_size, void* d_ws,
                              size_t ws_size, hipStream_t stream) {
  const float* x      = (const float*)d_in[0];  // [1024,12,1024]
  const float* w_oh   = (const float*)d_in[1];
  const float* w_hp   = (const float*)d_in[2];
  const float* w_pp   = (const float*)d_in[3];  // [1024,1024] = [k][n]
  const float* w_pc   = (const float*)d_in[4];  // [1024,512]
  const float* w_cp   = (const float*)d_in[5];  // [512,1024]
  const float* bias_h = (const float*)d_in[6];
  const float* bias_p = (const float*)d_in[7];
  const float* bias_c = (const float*)d_in[8];
  float* out = (float*)d_out;

  uint8_t* p = (uint8_t*)d_ws;
  _Float16* Wrf  = (_Float16*)p; p += (size_t)1024 * 1536 * 2;  // frag-packed
  _Float16* Wcf  = (_Float16*)p; p += (size_t)512 * 1024 * 2;   // frag-packed
  _Float16* WohT = (_Float16*)p; p += (size_t)1024 * 1024 * 2;
  _Float16* Whp  = (_Float16*)p; p += (size_t)1024 * 1024 * 2;
  _Float16* U    = (_Float16*)p; p += (size_t)11 * 1048576 * 2;
  _Float16* AH   = (_Float16*)p; p += (size_t)12 * 1048576 * 2;
  _Float16* Q    = (_Float16*)p; p += (size_t)12 * 1048576 * 2;
  _Float16* AP0  = (_Float16*)p; p += (size_t)1048576 * 2;
  _Float16* AP1  = (_Float16*)p; p += (size_t)1048576 * 2;
  _Float16* AC0  = (_Float16*)p; p += (size_t)512 * 1024 * 2;
  _Float16* AC1  = (_Float16*)p; p += (size_t)512 * 1024 * 2;
  float* Pst = (float*)p; p += (size_t)1048576 * 4;
  float* Cst = (float*)p; p += (size_t)512 * 1024 * 4;

  const dim3 blk256(256);
  // all weight prep in one dispatch
  k_wprep<<<dim3(1024), blk256, 0, stream>>>(w_oh, w_hp, w_pp, w_cp, w_pc,
                                             WohT, Whp, Wrf, Wcf);
  // input scan + state init
  k_prep<<<4096, blk256, 0, stream>>>(x, U, AH, AP0, AC0, Pst, Cst);
  // hoisted h GEMM -> AH[1..11]  (M=11264, 128x128 tiles, XCD-swizzled)
  k_gemm_big<<<dim3(8 * 88), blk256, 0, stream>>>(U, WohT, bias_h, AH, 0);
  // hoisted hp GEMM: Q_t = 0.25*(a_h_t @ w_hp + bias_p), all 12 t (M=12288)
  k_gemm_big<<<dim3(8 * 96), blk256, 0, stream>>>(AH, Whp, bias_p, Q, 1);
  // 12 sequential steps (1536 blocks = 6/CU)
  for (int t = 0; t < 12; ++t) {
    const _Float16* APc = (t & 1) ? AP1 : AP0;
    _Float16* APn       = (t & 1) ? AP0 : AP1;
    const _Float16* ACc = (t & 1) ? AC1 : AC0;
    _Float16* ACn       = (t & 1) ? AC0 : AC1;
    float* ot = (t >= 8) ? out + (size_t)(t - 8) * 1048576 : (float*)nullptr;
    k_step<<<dim3(1536), blk256, 0, stream>>>(Q + (size_t)t * 1048576, APc,
                                              ACc, APn, ACn, Wrf, Wcf, bias_c,
                                              Pst, Cst, ot);
  }
}

// Round 8
// 390.971 us; speedup vs baseline: 1.2565x; 1.2565x over previous
//
#include <hip/hip_runtime.h>
#include <cstdint>
#include <cstddef>

// ---------------------------------------------------------------------------
// R13: identical to R12 (bench infra failed twice; no measurement taken).
//      - k_step: R10's proven 32x64/768-block form.
//      - k_wprep fusion kept from R11 (proven correct).
//      - k_gemm_big retiled 128x128 -> 128x64: grid 704/768 (2.75/CU,
//        measured Occupancy 22%, MfmaUtil 18%) -> 1408/1536 (5.5-6/CU).
//        B traffic unchanged; extra A rereads are XCD-local L2 hits under
//        the kept y-chunk swizzle. LDS 24KB, launch_bounds(256,5).
// ---------------------------------------------------------------------------

typedef _Float16 half8 __attribute__((ext_vector_type(8)));
typedef float floatx4 __attribute__((ext_vector_type(4)));

__device__ __forceinline__ void async_cp16(const void* g, void* l) {
  __builtin_amdgcn_global_load_lds(
      (const __attribute__((address_space(1))) void*)g,
      (__attribute__((address_space(3))) void*)l, 16, 0, 0);
}

__device__ __forceinline__ float sigmoidf_(float x) {
  return 1.f / (1.f + __expf(-x));
}

// ---- transpose fp32 [K][N] tile -> f16 dst[n][k]
__device__ __forceinline__ void transpose_dev(
    const float* __restrict__ src, int N, _Float16* __restrict__ dst,
    int dst_ld, int k_off, int bx, int by, float (*tile)[65]) {
  const int k0 = by * 64, n0 = bx * 64;
  const int tx = threadIdx.x & 63, ty = threadIdx.x >> 6;
#pragma unroll
  for (int j = 0; j < 16; ++j) {
    int kr = j * 4 + ty;
    tile[kr][tx] = src[(size_t)(k0 + kr) * N + n0 + tx];
  }
  __syncthreads();
#pragma unroll
  for (int j = 0; j < 16; ++j) {
    int nr = j * 4 + ty;
    dst[(size_t)(n0 + nr) * dst_ld + k_off + k0 + tx] = (_Float16)tile[tx][nr];
  }
}

// ---- pack fp32 src [K][N] tile into MFMA B-fragment order f16
__device__ __forceinline__ void pack_dev(
    const float* __restrict__ src, int N, _Float16* __restrict__ dst,
    int kStride, int kOffChunks, int bx, int by, float (*tile)[65]) {
  const int k0 = by * 64, n0 = bx * 64;
  const int tx = threadIdx.x & 63, ty = threadIdx.x >> 6;
#pragma unroll
  for (int jj = 0; jj < 16; ++jj) {
    int kr = jj * 4 + ty;
    tile[kr][tx] = src[(size_t)(k0 + kr) * N + n0 + tx];
  }
  __syncthreads();
  const int j = threadIdx.x >> 6, lane = threadIdx.x & 63;
  const int r16 = lane & 15, quad = lane >> 4;
#pragma unroll
  for (int c = 0; c < 2; ++c) {
    half8 v;
#pragma unroll
    for (int u = 0; u < 8; ++u)
      v[u] = (_Float16)tile[c * 32 + quad * 8 + u][j * 16 + r16];
    const int kcG = kOffChunks + by * 2 + c;
    *(half8*)(dst + ((size_t)(bx * kStride + kcG) * 4 + j) * 512 + lane * 8) = v;
  }
}

// ---- all weight prep in one dispatch (ranges of the 1024-block grid)
__global__ __launch_bounds__(256) void k_wprep(
    const float* __restrict__ w_oh, const float* __restrict__ w_hp,
    const float* __restrict__ w_pp, const float* __restrict__ w_cp,
    const float* __restrict__ w_pc, _Float16* __restrict__ WohT,
    _Float16* __restrict__ Whp, _Float16* __restrict__ Wrf,
    _Float16* __restrict__ Wcf) {
  __shared__ float tile[64][65];
  const int blk = blockIdx.x;
  if (blk < 256) {
    transpose_dev(w_oh, 1024, WohT, 1024, 0, blk & 15, blk >> 4, tile);
  } else if (blk < 512) {
    const int t = blk - 256;
    transpose_dev(w_hp, 1024, Whp, 1024, 0, t & 15, t >> 4, tile);
  } else if (blk < 768) {
    const int t = blk - 512;
    pack_dev(w_pp, 1024, Wrf, 48, 0, t & 15, t >> 4, tile);
  } else if (blk < 896) {
    const int t = blk - 768;
    pack_dev(w_cp, 1024, Wrf, 48, 32, t & 15, t >> 4, tile);
  } else {
    const int t = blk - 896;
    pack_dev(w_pc, 512, Wcf, 32, 0, t & 7, t >> 3, tile);
  }
}

// ---- prefix scan over t of x (decay 0.75) -> U f16 [11][1024][1024]; inits
__global__ __launch_bounds__(256) void k_prep(
    const float* __restrict__ x, _Float16* __restrict__ U,
    _Float16* __restrict__ AH0, _Float16* __restrict__ AP0,
    _Float16* __restrict__ AC0, float* __restrict__ Pst,
    float* __restrict__ Cst) {
  const int id = blockIdx.x * 256 + threadIdx.x;  // 0 .. 1M-1
  const int b = id >> 10, i = id & 1023;
  const float* xb = x + (size_t)b * 12 * 1024 + i;
  float g = 0.f;
#pragma unroll
  for (int t = 0; t < 11; ++t) {
    g = xb[t * 1024] + 0.75f * g;
    U[(size_t)t * 1048576 + id] = (_Float16)g;
  }
  AH0[id] = (_Float16)0.5f;
  AP0[id] = (_Float16)0.5f;
  Pst[id] = 0.f;
  if (i < 512) {
    AC0[b * 512 + i] = (_Float16)0.5f;
    Cst[b * 512 + i] = 0.f;
  }
}

// ---- big GEMM, K=1024, 128x64 tile, 4 waves, BK=64 single-buffer LDS,
//      global_load_lds staging, 2-barrier K-loop, XCD y-chunk swizzle.
//      Grid: NX=16 x-blocks fastest within an XCD's contiguous y-chunk.
__global__ __launch_bounds__(256, 5) void k_gemm_big(
    const _Float16* __restrict__ A, const _Float16* __restrict__ B,
    const float* __restrict__ bias, _Float16* __restrict__ dst, int mode) {
  __shared__ __align__(16) _Float16 sA[128 * 64];  // 16 KB
  __shared__ __align__(16) _Float16 sB[64 * 64];   // 8 KB
  const int tid = threadIdx.x;
  const int lane = tid & 63, w = tid >> 6;
  const int lin = blockIdx.x;
  const int chunk = gridDim.x >> 7;  // = NY/8 (11 or 12)
  const int xcd = lin & 7;
  const int j0 = lin >> 3;
  const int bx = j0 & 15;
  const int by = xcd * chunk + (j0 >> 4);
  const int mBase = by * 128, nBase = bx * 64;
  const int r16 = lane & 15, quad = lane >> 4;
  const int lrow = lane >> 3;
  const int gsw = ((lane & 7) ^ lrow) * 8;
  const int wr = w >> 1, wc = w & 1;  // wr: 64-row half of A, wc: 32-col half

  const floatx4 zero = {0.f, 0.f, 0.f, 0.f};
  floatx4 acc[4][2];
#pragma unroll
  for (int i = 0; i < 4; ++i)
#pragma unroll
    for (int j = 0; j < 2; ++j) acc[i][j] = zero;

  // wave w stages A rows [w*32, w*32+32) (4 cp) and B rows [w*16, w*16+16) (2 cp)
  const _Float16* Abase = A + (size_t)(mBase + w * 32 + lrow) * 1024 + gsw;
  const _Float16* Bbase = B + (size_t)(nBase + w * 16 + lrow) * 1024 + gsw;
  _Float16* sAw = sA + (w * 32) * 64;
  _Float16* sBw = sB + (w * 16) * 64;
  const _Float16* sa = sA + (size_t)wr * 64 * 64;
  const _Float16* sb = sB + (size_t)wc * 32 * 64;

  for (int kt = 0; kt < 16; ++kt) {
    const int k0 = kt << 6;
#pragma unroll
    for (int q = 0; q < 4; ++q)
      async_cp16(Abase + (size_t)q * 8192 + k0, sAw + q * 512);
#pragma unroll
    for (int q = 0; q < 2; ++q)
      async_cp16(Bbase + (size_t)q * 8192 + k0, sBw + q * 512);
    asm volatile("s_waitcnt vmcnt(0)" ::: "memory");
    __syncthreads();
#pragma unroll
    for (int kk = 0; kk < 2; ++kk) {
      const int sw = ((kk * 4 + quad) ^ (r16 & 7)) * 8;
      half8 af[4], bf[2];
#pragma unroll
      for (int i = 0; i < 4; ++i)
        af[i] = *(const half8*)&sa[(i * 16 + r16) * 64 + sw];
#pragma unroll
      for (int j = 0; j < 2; ++j)
        bf[j] = *(const half8*)&sb[(j * 16 + r16) * 64 + sw];
#pragma unroll
      for (int i = 0; i < 4; ++i)
#pragma unroll
        for (int j = 0; j < 2; ++j)
          acc[i][j] = __builtin_amdgcn_mfma_f32_16x16x32_f16(af[i], bf[j],
                                                             acc[i][j], 0, 0, 0);
    }
    __syncthreads();
  }

  if (mode == 0) {
    const int tm1 = mBase >> 10;
    const float beta = 1.f - __powf(0.75f, (float)(tm1 + 1));
    _Float16* o = dst + (size_t)(mBase + 1024) * 1024;
#pragma unroll
    for (int i = 0; i < 4; ++i)
#pragma unroll
      for (int j = 0; j < 2; ++j) {
        const int n = nBase + wc * 32 + j * 16 + r16;
#pragma unroll
        for (int r = 0; r < 4; ++r) {
          const int row = wr * 64 + i * 16 + quad * 4 + r;
          const float h = 0.25f * acc[i][j][r] + beta * bias[n];
          o[(size_t)row * 1024 + n] = (_Float16)sigmoidf_(h);
        }
      }
  } else {
    _Float16* o = dst + (size_t)mBase * 1024;
#pragma unroll
    for (int i = 0; i < 4; ++i)
#pragma unroll
      for (int j = 0; j < 2; ++j) {
        const int n = nBase + wc * 32 + j * 16 + r16;
#pragma unroll
        for (int r = 0; r < 4; ++r) {
          const int row = wr * 64 + i * 16 + quad * 4 + r;
          o[(size_t)row * 1024 + n] = (_Float16)(0.25f * (acc[i][j][r] + bias[n]));
        }
      }
  }
}

// ---- one recurrent step: 4-wave split-K blocks, LDS reduce. (R10 proven)
// blocks 0..511:  P tiles 32m x 64n, K=1536 (12 chunks/wave) over [a_p|a_c]
// blocks 512..767: C tiles 32m x 64n, K=1024 (8 chunks/wave) over a_p
__global__ __launch_bounds__(256, 3) void k_step(
    const _Float16* __restrict__ Qt, const _Float16* __restrict__ APc,
    const _Float16* __restrict__ ACc, _Float16* __restrict__ APn,
    _Float16* __restrict__ ACn, const _Float16* __restrict__ Wrf,
    const _Float16* __restrict__ Wcf, const float* __restrict__ bias_c,
    float* __restrict__ Pst, float* __restrict__ Cst,
    float* __restrict__ out_t) {
  __shared__ float red[4][2][4][4][64];  // 32 KB
  const int lane = threadIdx.x & 63, w = threadIdx.x >> 6;
  const int r16 = lane & 15, quad = lane >> 4;
  const int blk = blockIdx.x;
  const bool isP = blk < 512;
  int mBase, nt;
  if (isP) {
    mBase = (blk >> 4) * 32;
    nt = blk & 15;
  } else {
    const int b = blk - 512;
    mBase = (b >> 3) * 32;
    nt = b & 7;
  }
  const int nBase = nt * 64;
  const floatx4 zero = {0.f, 0.f, 0.f, 0.f};
  floatx4 acc[2][4];
#pragma unroll
  for (int i = 0; i < 2; ++i)
#pragma unroll
    for (int j = 0; j < 4; ++j) acc[i][j] = zero;

  half8 abuf[4][2], bbuf[4][4];
  auto MM = [&](half8* af, half8* bf) {
#pragma unroll
    for (int i = 0; i < 2; ++i)
#pragma unroll
      for (int j = 0; j < 4; ++j)
        acc[i][j] = __builtin_amdgcn_mfma_f32_16x16x32_f16(af[i], bf[j],
                                                           acc[i][j], 0, 0, 0);
  };

  if (isP) {
    const int kcBase = w * 12;
    auto LDA = [&](int c) {
      const int kc = kcBase + c, kg = kc * 32;
      half8* af = abuf[c & 3];
      if (kc < 32) {
        af[0] = *(const half8*)(APc + (size_t)(mBase + r16) * 1024 + kg + quad * 8);
        af[1] = *(const half8*)(APc + (size_t)(mBase + 16 + r16) * 1024 + kg + quad * 8);
      } else {
        af[0] = *(const half8*)(ACc + (size_t)(mBase + r16) * 512 + (kg - 1024) + quad * 8);
        af[1] = *(const half8*)(ACc + (size_t)(mBase + 16 + r16) * 512 + (kg - 1024) + quad * 8);
      }
    };
    auto LDB = [&](int c) {
      const int kc = kcBase + c;
      const _Float16* wp = Wrf + (size_t)(nt * 48 + kc) * 2048 + lane * 8;
      half8* bf = bbuf[c & 3];
#pragma unroll
      for (int j = 0; j < 4; ++j) bf[j] = *(const half8*)(wp + j * 512);
    };
    LDA(0); LDA(1); LDA(2); LDA(3);
    LDB(0); LDB(1); LDB(2);
#pragma unroll
    for (int c = 0; c < 12; ++c) {
      if (c + 3 < 12) LDB(c + 3);
      MM(abuf[c & 3], bbuf[c & 3]);
      if (c + 4 < 12) LDA(c + 4);
    }
  } else {
    const int kcBase = w * 8;
    auto LDA = [&](int c) {
      const int kc = kcBase + c, kg = kc * 32;
      half8* af = abuf[c & 3];
      af[0] = *(const half8*)(APc + (size_t)(mBase + r16) * 1024 + kg + quad * 8);
      af[1] = *(const half8*)(APc + (size_t)(mBase + 16 + r16) * 1024 + kg + quad * 8);
    };
    auto LDB = [&](int c) {
      const int kc = kcBase + c;
      const _Float16* wp = Wcf + (size_t)(nt * 32 + kc) * 2048 + lane * 8;
      half8* bf = bbuf[c & 3];
#pragma unroll
      for (int j = 0; j < 4; ++j) bf[j] = *(const half8*)(wp + j * 512);
    };
    LDA(0); LDA(1); LDA(2); LDA(3);
    LDB(0); LDB(1); LDB(2);
#pragma unroll
    for (int c = 0; c < 8; ++c) {
      if (c + 3 < 8) LDB(c + 3);
      MM(abuf[c & 3], bbuf[c & 3]);
      if (c + 4 < 8) LDA(c + 4);
    }
  }

  // ---- epilogue operand prefetch (rides across the reduction barrier)
  const int n_ep = nBase + w * 16 + r16;
  _Float16 qv[2][4];
  float sv[2][4];
  float biasn = 0.f;
  if (isP) {
#pragma unroll
    for (int i = 0; i < 2; ++i)
#pragma unroll
      for (int r = 0; r < 4; ++r) {
        const size_t o = (size_t)(mBase + i * 16 + quad * 4 + r) * 1024 + n_ep;
        qv[i][r] = Qt[o];
        sv[i][r] = Pst[o];
      }
  } else {
    biasn = bias_c[n_ep];
#pragma unroll
    for (int i = 0; i < 2; ++i)
#pragma unroll
      for (int r = 0; r < 4; ++r) {
        const size_t o = (size_t)(mBase + i * 16 + quad * 4 + r) * 512 + n_ep;
        sv[i][r] = Cst[o];
      }
  }

  // cross-wave K reduction (raw barrier: wait own ds_writes only, no vm drain)
#pragma unroll
  for (int i = 0; i < 2; ++i)
#pragma unroll
    for (int j = 0; j < 4; ++j)
#pragma unroll
      for (int r = 0; r < 4; ++r) red[w][i][j][r][lane] = acc[i][j][r];
  asm volatile("s_waitcnt lgkmcnt(0)" ::: "memory");
  __builtin_amdgcn_s_barrier();

  if (isP) {
#pragma unroll
    for (int i = 0; i < 2; ++i) {
#pragma unroll
      for (int r = 0; r < 4; ++r) {
        float v = 0.f;
#pragma unroll
        for (int q = 0; q < 4; ++q) v += red[q][i][w][r][lane];
        const int b = mBase + i * 16 + quad * 4 + r;
        const size_t o = (size_t)b * 1024 + n_ep;
        const float pn = 0.25f * v + (float)qv[i][r] + 0.75f * sv[i][r];
        Pst[o] = pn;
        const float a = sigmoidf_(pn);
        APn[o] = (_Float16)a;
        if (out_t) out_t[o] = a;
      }
    }
  } else {
#pragma unroll
    for (int i = 0; i < 2; ++i) {
#pragma unroll
      for (int r = 0; r < 4; ++r) {
        float v = 0.f;
#pragma unroll
        for (int q = 0; q < 4; ++q) v += red[q][i][w][r][lane];
        const int b = mBase + i * 16 + quad * 4 + r;
        const size_t o = (size_t)b * 512 + n_ep;
        const float cn = 0.25f * (v + biasn) + 0.75f * sv[i][r];
        Cst[o] = cn;
        ACn[o] = (_Float16)sigmoidf_(cn);
      }
    }
  }
}

extern "C" void kernel_launch(void* const* d_in, const int* in_sizes, int n_in,
                              void* d_out, int out_size, void* d_ws,
                              size_t ws_size, hipStream_t stream) {
  const float* x      = (const float*)d_in[0];  // [1024,12,1024]
  const float* w_oh   = (const float*)d_in[1];
  const float* w_hp   = (const float*)d_in[2];
  const float* w_pp   = (const float*)d_in[3];  // [1024,1024] = [k][n]
  const float* w_pc   = (const float*)d_in[4];  // [1024,512]
  const float* w_cp   = (const float*)d_in[5];  // [512,1024]
  const float* bias_h = (const float*)d_in[6];
  const float* bias_p = (const float*)d_in[7];
  const float* bias_c = (const float*)d_in[8];
  float* out = (float*)d_out;

  uint8_t* p = (uint8_t*)d_ws;
  _Float16* Wrf  = (_Float16*)p; p += (size_t)1024 * 1536 * 2;  // frag-packed
  _Float16* Wcf  = (_Float16*)p; p += (size_t)512 * 1024 * 2;   // frag-packed
  _Float16* WohT = (_Float16*)p; p += (size_t)1024 * 1024 * 2;
  _Float16* Whp  = (_Float16*)p; p += (size_t)1024 * 1024 * 2;
  _Float16* U    = (_Float16*)p; p += (size_t)11 * 1048576 * 2;
  _Float16* AH   = (_Float16*)p; p += (size_t)12 * 1048576 * 2;
  _Float16* Q    = (_Float16*)p; p += (size_t)12 * 1048576 * 2;
  _Float16* AP0  = (_Float16*)p; p += (size_t)1048576 * 2;
  _Float16* AP1  = (_Float16*)p; p += (size_t)1048576 * 2;
  _Float16* AC0  = (_Float16*)p; p += (size_t)512 * 1024 * 2;
  _Float16* AC1  = (_Float16*)p; p += (size_t)512 * 1024 * 2;
  float* Pst = (float*)p; p += (size_t)1048576 * 4;
  float* Cst = (float*)p; p += (size_t)512 * 1024 * 4;

  const dim3 blk256(256);
  // all weight prep in one dispatch
  k_wprep<<<dim3(1024), blk256, 0, stream>>>(w_oh, w_hp, w_pp, w_cp, w_pc,
                                             WohT, Whp, Wrf, Wcf);
  // input scan + state init
  k_prep<<<4096, blk256, 0, stream>>>(x, U, AH, AP0, AC0, Pst, Cst);
  // hoisted h GEMM -> AH[1..11]  (M=11264, 128x64 tiles, XCD-swizzled)
  k_gemm_big<<<dim3(16 * 88), blk256, 0, stream>>>(U, WohT, bias_h, AH, 0);
  // hoisted hp GEMM: Q_t = 0.25*(a_h_t @ w_hp + bias_p), all 12 t (M=12288)
  k_gemm_big<<<dim3(16 * 96), blk256, 0, stream>>>(AH, Whp, bias_p, Q, 1);
  // 12 sequential steps (768 blocks = 3/CU)
  for (int t = 0; t < 12; ++t) {
    const _Float16* APc = (t & 1) ? AP1 : AP0;
    _Float16* APn       = (t & 1) ? AP0 : AP1;
    const _Float16* ACc = (t & 1) ? AC1 : AC0;
    _Float16* ACn       = (t & 1) ? AC0 : AC1;
    float* ot = (t >= 8) ? out + (size_t)(t - 8) * 1048576 : (float*)nullptr;
    k_step<<<dim3(768), blk256, 0, stream>>>(Q + (size_t)t * 1048576, APc,
                                             ACc, APn, ACn, Wrf, Wcf, bias_c,
                                             Pst, Cst, ot);
  }
}

// Round 9
// 372.731 us; speedup vs baseline: 1.3180x; 1.0489x over previous
//
#include <hip/hip_runtime.h>
#include <cstdint>
#include <cstddef>

// ---------------------------------------------------------------------------
// R14: - k_gemm_big reverted to R10's proven 128x128 form (R13's 128x64
//        retile neutral-to-negative: occupancy gain offset by doubled
//        prologue/drain + A rereads; gemm is at its structural local opt).
//      - k_step: asymmetric prefetch. A-loads are cross-XCD activations
//        (~500-900cy, written by prev dispatch on other XCDs); B-loads are
//        XCD-local L2 weights (~200cy). A-ring deepened 4->6 slots
//        (5 ahead), B-ring kept 4-deep. ~169 VGPR = 3 waves/SIMD cap.
//      - k_wprep fusion, epilogue prefetch, raw-barrier reduction kept.
// ---------------------------------------------------------------------------

typedef _Float16 half8 __attribute__((ext_vector_type(8)));
typedef float floatx4 __attribute__((ext_vector_type(4)));

__device__ __forceinline__ void async_cp16(const void* g, void* l) {
  __builtin_amdgcn_global_load_lds(
      (const __attribute__((address_space(1))) void*)g,
      (__attribute__((address_space(3))) void*)l, 16, 0, 0);
}

__device__ __forceinline__ float sigmoidf_(float x) {
  return 1.f / (1.f + __expf(-x));
}

// ---- transpose fp32 [K][N] tile -> f16 dst[n][k]
__device__ __forceinline__ void transpose_dev(
    const float* __restrict__ src, int N, _Float16* __restrict__ dst,
    int dst_ld, int k_off, int bx, int by, float (*tile)[65]) {
  const int k0 = by * 64, n0 = bx * 64;
  const int tx = threadIdx.x & 63, ty = threadIdx.x >> 6;
#pragma unroll
  for (int j = 0; j < 16; ++j) {
    int kr = j * 4 + ty;
    tile[kr][tx] = src[(size_t)(k0 + kr) * N + n0 + tx];
  }
  __syncthreads();
#pragma unroll
  for (int j = 0; j < 16; ++j) {
    int nr = j * 4 + ty;
    dst[(size_t)(n0 + nr) * dst_ld + k_off + k0 + tx] = (_Float16)tile[tx][nr];
  }
}

// ---- pack fp32 src [K][N] tile into MFMA B-fragment order f16
__device__ __forceinline__ void pack_dev(
    const float* __restrict__ src, int N, _Float16* __restrict__ dst,
    int kStride, int kOffChunks, int bx, int by, float (*tile)[65]) {
  const int k0 = by * 64, n0 = bx * 64;
  const int tx = threadIdx.x & 63, ty = threadIdx.x >> 6;
#pragma unroll
  for (int jj = 0; jj < 16; ++jj) {
    int kr = jj * 4 + ty;
    tile[kr][tx] = src[(size_t)(k0 + kr) * N + n0 + tx];
  }
  __syncthreads();
  const int j = threadIdx.x >> 6, lane = threadIdx.x & 63;
  const int r16 = lane & 15, quad = lane >> 4;
#pragma unroll
  for (int c = 0; c < 2; ++c) {
    half8 v;
#pragma unroll
    for (int u = 0; u < 8; ++u)
      v[u] = (_Float16)tile[c * 32 + quad * 8 + u][j * 16 + r16];
    const int kcG = kOffChunks + by * 2 + c;
    *(half8*)(dst + ((size_t)(bx * kStride + kcG) * 4 + j) * 512 + lane * 8) = v;
  }
}

// ---- all weight prep in one dispatch (ranges of the 1024-block grid)
__global__ __launch_bounds__(256) void k_wprep(
    const float* __restrict__ w_oh, const float* __restrict__ w_hp,
    const float* __restrict__ w_pp, const float* __restrict__ w_cp,
    const float* __restrict__ w_pc, _Float16* __restrict__ WohT,
    _Float16* __restrict__ Whp, _Float16* __restrict__ Wrf,
    _Float16* __restrict__ Wcf) {
  __shared__ float tile[64][65];
  const int blk = blockIdx.x;
  if (blk < 256) {
    transpose_dev(w_oh, 1024, WohT, 1024, 0, blk & 15, blk >> 4, tile);
  } else if (blk < 512) {
    const int t = blk - 256;
    transpose_dev(w_hp, 1024, Whp, 1024, 0, t & 15, t >> 4, tile);
  } else if (blk < 768) {
    const int t = blk - 512;
    pack_dev(w_pp, 1024, Wrf, 48, 0, t & 15, t >> 4, tile);
  } else if (blk < 896) {
    const int t = blk - 768;
    pack_dev(w_cp, 1024, Wrf, 48, 32, t & 15, t >> 4, tile);
  } else {
    const int t = blk - 896;
    pack_dev(w_pc, 512, Wcf, 32, 0, t & 7, t >> 3, tile);
  }
}

// ---- prefix scan over t of x (decay 0.75) -> U f16 [11][1024][1024]; inits
__global__ __launch_bounds__(256) void k_prep(
    const float* __restrict__ x, _Float16* __restrict__ U,
    _Float16* __restrict__ AH0, _Float16* __restrict__ AP0,
    _Float16* __restrict__ AC0, float* __restrict__ Pst,
    float* __restrict__ Cst) {
  const int id = blockIdx.x * 256 + threadIdx.x;  // 0 .. 1M-1
  const int b = id >> 10, i = id & 1023;
  const float* xb = x + (size_t)b * 12 * 1024 + i;
  float g = 0.f;
#pragma unroll
  for (int t = 0; t < 11; ++t) {
    g = xb[t * 1024] + 0.75f * g;
    U[(size_t)t * 1048576 + id] = (_Float16)g;
  }
  AH0[id] = (_Float16)0.5f;
  AP0[id] = (_Float16)0.5f;
  Pst[id] = 0.f;
  if (i < 512) {
    AC0[b * 512 + i] = (_Float16)0.5f;
    Cst[b * 512 + i] = 0.f;
  }
}

// ---- big GEMM, K=1024, 128x128 tile, 4 waves, BK=64 single-buffer LDS,
//      global_load_lds staging, 2-barrier K-loop, XCD y-chunk swizzle. (R10)
__global__ __launch_bounds__(256, 3) void k_gemm_big(
    const _Float16* __restrict__ A, const _Float16* __restrict__ B,
    const float* __restrict__ bias, _Float16* __restrict__ dst, int mode) {
  __shared__ __align__(16) _Float16 sA[128 * 64];
  __shared__ __align__(16) _Float16 sB[128 * 64];
  const int tid = threadIdx.x;
  const int lane = tid & 63, w = tid >> 6;
  const int lin = blockIdx.x;
  const int chunk = gridDim.x >> 6;  // = NY/8 (11 or 12)
  const int xcd = lin & 7;
  const int j0 = lin >> 3;
  const int bx = j0 & 7;
  const int by = xcd * chunk + (j0 >> 3);
  const int mBase = by * 128, nBase = bx * 128;
  const int r16 = lane & 15, quad = lane >> 4;
  const int lrow = lane >> 3;
  const int gsw = ((lane & 7) ^ lrow) * 8;
  const int wr = w >> 1, wc = w & 1;

  const floatx4 zero = {0.f, 0.f, 0.f, 0.f};
  floatx4 acc[4][4];
#pragma unroll
  for (int i = 0; i < 4; ++i)
#pragma unroll
    for (int j = 0; j < 4; ++j) acc[i][j] = zero;

  const _Float16* Abase = A + (size_t)(mBase + w * 32 + lrow) * 1024 + gsw;
  const _Float16* Bbase = B + (size_t)(nBase + w * 32 + lrow) * 1024 + gsw;
  _Float16* sAw = sA + (w * 32) * 64;
  _Float16* sBw = sB + (w * 32) * 64;
  const _Float16* sa = sA + (size_t)wr * 64 * 64;
  const _Float16* sb = sB + (size_t)wc * 64 * 64;

  for (int kt = 0; kt < 16; ++kt) {
    const int k0 = kt << 6;
#pragma unroll
    for (int q = 0; q < 4; ++q)
      async_cp16(Abase + (size_t)q * 8192 + k0, sAw + q * 512);
#pragma unroll
    for (int q = 0; q < 4; ++q)
      async_cp16(Bbase + (size_t)q * 8192 + k0, sBw + q * 512);
    asm volatile("s_waitcnt vmcnt(0)" ::: "memory");
    __syncthreads();
#pragma unroll
    for (int kk = 0; kk < 2; ++kk) {
      const int sw = ((kk * 4 + quad) ^ (r16 & 7)) * 8;
      half8 af[4], bf[4];
#pragma unroll
      for (int i = 0; i < 4; ++i)
        af[i] = *(const half8*)&sa[(i * 16 + r16) * 64 + sw];
#pragma unroll
      for (int j = 0; j < 4; ++j)
        bf[j] = *(const half8*)&sb[(j * 16 + r16) * 64 + sw];
#pragma unroll
      for (int i = 0; i < 4; ++i)
#pragma unroll
        for (int j = 0; j < 4; ++j)
          acc[i][j] = __builtin_amdgcn_mfma_f32_16x16x32_f16(af[i], bf[j],
                                                             acc[i][j], 0, 0, 0);
    }
    __syncthreads();
  }

  if (mode == 0) {
    const int tm1 = mBase >> 10;
    const float beta = 1.f - __powf(0.75f, (float)(tm1 + 1));
    _Float16* o = dst + (size_t)(mBase + 1024) * 1024;
#pragma unroll
    for (int i = 0; i < 4; ++i)
#pragma unroll
      for (int j = 0; j < 4; ++j) {
        const int n = nBase + wc * 64 + j * 16 + r16;
#pragma unroll
        for (int r = 0; r < 4; ++r) {
          const int row = wr * 64 + i * 16 + quad * 4 + r;
          const float h = 0.25f * acc[i][j][r] + beta * bias[n];
          o[(size_t)row * 1024 + n] = (_Float16)sigmoidf_(h);
        }
      }
  } else {
    _Float16* o = dst + (size_t)mBase * 1024;
#pragma unroll
    for (int i = 0; i < 4; ++i)
#pragma unroll
      for (int j = 0; j < 4; ++j) {
        const int n = nBase + wc * 64 + j * 16 + r16;
#pragma unroll
        for (int r = 0; r < 4; ++r) {
          const int row = wr * 64 + i * 16 + quad * 4 + r;
          o[(size_t)row * 1024 + n] = (_Float16)(0.25f * (acc[i][j][r] + bias[n]));
        }
      }
  }
}

// ---- one recurrent step: 4-wave split-K blocks, LDS reduce.
// blocks 0..511:  P tiles 32m x 64n, K=1536 (12 chunks/wave) over [a_p|a_c]
// blocks 512..767: C tiles 32m x 64n, K=1024 (8 chunks/wave) over a_p
// A via 6-slot VGPR ring (5 ahead; cross-XCD activation latency), B via
// 4-slot ring (3 ahead; XCD-local L2 weights). Epilogue operands prefetched
// before the raw-barrier reduction (no vm drain).
__global__ __launch_bounds__(256, 3) void k_step(
    const _Float16* __restrict__ Qt, const _Float16* __restrict__ APc,
    const _Float16* __restrict__ ACc, _Float16* __restrict__ APn,
    _Float16* __restrict__ ACn, const _Float16* __restrict__ Wrf,
    const _Float16* __restrict__ Wcf, const float* __restrict__ bias_c,
    float* __restrict__ Pst, float* __restrict__ Cst,
    float* __restrict__ out_t) {
  __shared__ float red[4][2][4][4][64];  // 32 KB
  const int lane = threadIdx.x & 63, w = threadIdx.x >> 6;
  const int r16 = lane & 15, quad = lane >> 4;
  const int blk = blockIdx.x;
  const bool isP = blk < 512;
  int mBase, nt;
  if (isP) {
    mBase = (blk >> 4) * 32;
    nt = blk & 15;
  } else {
    const int b = blk - 512;
    mBase = (b >> 3) * 32;
    nt = b & 7;
  }
  const int nBase = nt * 64;
  const floatx4 zero = {0.f, 0.f, 0.f, 0.f};
  floatx4 acc[2][4];
#pragma unroll
  for (int i = 0; i < 2; ++i)
#pragma unroll
    for (int j = 0; j < 4; ++j) acc[i][j] = zero;

  half8 abuf[6][2], bbuf[4][4];
  auto MM = [&](half8* af, half8* bf) {
#pragma unroll
    for (int i = 0; i < 2; ++i)
#pragma unroll
      for (int j = 0; j < 4; ++j)
        acc[i][j] = __builtin_amdgcn_mfma_f32_16x16x32_f16(af[i], bf[j],
                                                           acc[i][j], 0, 0, 0);
  };

  if (isP) {
    const int kcBase = w * 12;
    auto LDA = [&](int c) {
      const int kc = kcBase + c, kg = kc * 32;
      half8* af = abuf[c % 6];
      if (kc < 32) {
        af[0] = *(const half8*)(APc + (size_t)(mBase + r16) * 1024 + kg + quad * 8);
        af[1] = *(const half8*)(APc + (size_t)(mBase + 16 + r16) * 1024 + kg + quad * 8);
      } else {
        af[0] = *(const half8*)(ACc + (size_t)(mBase + r16) * 512 + (kg - 1024) + quad * 8);
        af[1] = *(const half8*)(ACc + (size_t)(mBase + 16 + r16) * 512 + (kg - 1024) + quad * 8);
      }
    };
    auto LDB = [&](int c) {
      const int kc = kcBase + c;
      const _Float16* wp = Wrf + (size_t)(nt * 48 + kc) * 2048 + lane * 8;
      half8* bf = bbuf[c & 3];
#pragma unroll
      for (int j = 0; j < 4; ++j) bf[j] = *(const half8*)(wp + j * 512);
    };
    LDA(0); LDA(1); LDA(2); LDA(3); LDA(4); LDA(5);
    LDB(0); LDB(1); LDB(2);
#pragma unroll
    for (int c = 0; c < 12; ++c) {
      if (c + 3 < 12) LDB(c + 3);
      MM(abuf[c % 6], bbuf[c & 3]);
      if (c + 6 < 12) LDA(c + 6);
    }
  } else {
    const int kcBase = w * 8;
    auto LDA = [&](int c) {
      const int kc = kcBase + c, kg = kc * 32;
      half8* af = abuf[c % 6];
      af[0] = *(const half8*)(APc + (size_t)(mBase + r16) * 1024 + kg + quad * 8);
      af[1] = *(const half8*)(APc + (size_t)(mBase + 16 + r16) * 1024 + kg + quad * 8);
    };
    auto LDB = [&](int c) {
      const int kc = kcBase + c;
      const _Float16* wp = Wcf + (size_t)(nt * 32 + kc) * 2048 + lane * 8;
      half8* bf = bbuf[c & 3];
#pragma unroll
      for (int j = 0; j < 4; ++j) bf[j] = *(const half8*)(wp + j * 512);
    };
    LDA(0); LDA(1); LDA(2); LDA(3); LDA(4); LDA(5);
    LDB(0); LDB(1); LDB(2);
#pragma unroll
    for (int c = 0; c < 8; ++c) {
      if (c + 3 < 8) LDB(c + 3);
      MM(abuf[c % 6], bbuf[c & 3]);
      if (c + 6 < 8) LDA(c + 6);
    }
  }

  // ---- epilogue operand prefetch (rides across the reduction barrier)
  const int n_ep = nBase + w * 16 + r16;
  _Float16 qv[2][4];
  float sv[2][4];
  float biasn = 0.f;
  if (isP) {
#pragma unroll
    for (int i = 0; i < 2; ++i)
#pragma unroll
      for (int r = 0; r < 4; ++r) {
        const size_t o = (size_t)(mBase + i * 16 + quad * 4 + r) * 1024 + n_ep;
        qv[i][r] = Qt[o];
        sv[i][r] = Pst[o];
      }
  } else {
    biasn = bias_c[n_ep];
#pragma unroll
    for (int i = 0; i < 2; ++i)
#pragma unroll
      for (int r = 0; r < 4; ++r) {
        const size_t o = (size_t)(mBase + i * 16 + quad * 4 + r) * 512 + n_ep;
        sv[i][r] = Cst[o];
      }
  }

  // cross-wave K reduction (raw barrier: wait own ds_writes only, no vm drain)
#pragma unroll
  for (int i = 0; i < 2; ++i)
#pragma unroll
    for (int j = 0; j < 4; ++j)
#pragma unroll
      for (int r = 0; r < 4; ++r) red[w][i][j][r][lane] = acc[i][j][r];
  asm volatile("s_waitcnt lgkmcnt(0)" ::: "memory");
  __builtin_amdgcn_s_barrier();

  if (isP) {
#pragma unroll
    for (int i = 0; i < 2; ++i) {
#pragma unroll
      for (int r = 0; r < 4; ++r) {
        float v = 0.f;
#pragma unroll
        for (int q = 0; q < 4; ++q) v += red[q][i][w][r][lane];
        const int b = mBase + i * 16 + quad * 4 + r;
        const size_t o = (size_t)b * 1024 + n_ep;
        const float pn = 0.25f * v + (float)qv[i][r] + 0.75f * sv[i][r];
        Pst[o] = pn;
        const float a = sigmoidf_(pn);
        APn[o] = (_Float16)a;
        if (out_t) out_t[o] = a;
      }
    }
  } else {
#pragma unroll
    for (int i = 0; i < 2; ++i) {
#pragma unroll
      for (int r = 0; r < 4; ++r) {
        float v = 0.f;
#pragma unroll
        for (int q = 0; q < 4; ++q) v += red[q][i][w][r][lane];
        const int b = mBase + i * 16 + quad * 4 + r;
        const size_t o = (size_t)b * 512 + n_ep;
        const float cn = 0.25f * (v + biasn) + 0.75f * sv[i][r];
        Cst[o] = cn;
        ACn[o] = (_Float16)sigmoidf_(cn);
      }
    }
  }
}

extern "C" void kernel_launch(void* const* d_in, const int* in_sizes, int n_in,
                              void* d_out, int out_size, void* d_ws,
                              size_t ws_size, hipStream_t stream) {
  const float* x      = (const float*)d_in[0];  // [1024,12,1024]
  const float* w_oh   = (const float*)d_in[1];
  const float* w_hp   = (const float*)d_in[2];
  const float* w_pp   = (const float*)d_in[3];  // [1024,1024] = [k][n]
  const float* w_pc   = (const float*)d_in[4];  // [1024,512]
  const float* w_cp   = (const float*)d_in[5];  // [512,1024]
  const float* bias_h = (const float*)d_in[6];
  const float* bias_p = (const float*)d_in[7];
  const float* bias_c = (const float*)d_in[8];
  float* out = (float*)d_out;

  uint8_t* p = (uint8_t*)d_ws;
  _Float16* Wrf  = (_Float16*)p; p += (size_t)1024 * 1536 * 2;  // frag-packed
  _Float16* Wcf  = (_Float16*)p; p += (size_t)512 * 1024 * 2;   // frag-packed
  _Float16* WohT = (_Float16*)p; p += (size_t)1024 * 1024 * 2;
  _Float16* Whp  = (_Float16*)p; p += (size_t)1024 * 1024 * 2;
  _Float16* U    = (_Float16*)p; p += (size_t)11 * 1048576 * 2;
  _Float16* AH   = (_Float16*)p; p += (size_t)12 * 1048576 * 2;
  _Float16* Q    = (_Float16*)p; p += (size_t)12 * 1048576 * 2;
  _Float16* AP0  = (_Float16*)p; p += (size_t)1048576 * 2;
  _Float16* AP1  = (_Float16*)p; p += (size_t)1048576 * 2;
  _Float16* AC0  = (_Float16*)p; p += (size_t)512 * 1024 * 2;
  _Float16* AC1  = (_Float16*)p; p += (size_t)512 * 1024 * 2;
  float* Pst = (float*)p; p += (size_t)1048576 * 4;
  float* Cst = (float*)p; p += (size_t)512 * 1024 * 4;

  const dim3 blk256(256);
  // all weight prep in one dispatch
  k_wprep<<<dim3(1024), blk256, 0, stream>>>(w_oh, w_hp, w_pp, w_cp, w_pc,
                                             WohT, Whp, Wrf, Wcf);
  // input scan + state init
  k_prep<<<4096, blk256, 0, stream>>>(x, U, AH, AP0, AC0, Pst, Cst);
  // hoisted h GEMM -> AH[1..11]  (M=11264, 128x128 tiles, XCD-swizzled)
  k_gemm_big<<<dim3(8 * 88), blk256, 0, stream>>>(U, WohT, bias_h, AH, 0);
  // hoisted hp GEMM: Q_t = 0.25*(a_h_t @ w_hp + bias_p), all 12 t (M=12288)
  k_gemm_big<<<dim3(8 * 96), blk256, 0, stream>>>(AH, Whp, bias_p, Q, 1);
  // 12 sequential steps (768 blocks = 3/CU)
  for (int t = 0; t < 12; ++t) {
    const _Float16* APc = (t & 1) ? AP1 : AP0;
    _Float16* APn       = (t & 1) ? AP0 : AP1;
    const _Float16* ACc = (t & 1) ? AC1 : AC0;
    _Float16* ACn       = (t & 1) ? AC0 : AC1;
    float* ot = (t >= 8) ? out + (size_t)(t - 8) * 1048576 : (float*)nullptr;
    k_step<<<dim3(768), blk256, 0, stream>>>(Q + (size_t)t * 1048576, APc,
                                             ACc, APn, ACn, Wrf, Wcf, bias_c,
                                             Pst, Cst, ot);
  }
}